// Round 1
// baseline (725.952 us; speedup 1.0000x reference)
//
#include <hip/hip_runtime.h>

#define REG_CONST 0.05f
#define NCLASS 10
#define DIM 128
#define TILE 64
#define NBLOCKS 768
#define NTHREADS 256

// async global->LDS, 16B per lane. LDS dest is wave-uniform base + lane*16.
__device__ __forceinline__ void async_ld16(const void* g, void* l) {
  __builtin_amdgcn_global_load_lds(
      (const __attribute__((address_space(1))) void*)g,
      (__attribute__((address_space(3))) void*)l, 16, 0, 0);
}

__global__ __launch_bounds__(NTHREADS, 3)
void svm_fused(const float* __restrict__ X, const int* __restrict__ y,
               const float* __restrict__ w, float* __restrict__ out,
               int ntiles, float inv_n) {
  // X tile: 64 rows x 32 float4, XOR-swizzled: slot(row,d4) = row*32 + (d4 ^ (row&31))
  __shared__ float4 xs[2048];      // 32 KiB
  __shared__ float4 coefs[192];    // 64 rows x 3 float4 (10 coef + 2 pad) = 3 KiB
  __shared__ float4 wlds4[360];    // w padded: float ofs = c*144 + d + 4*(d>>5) = 5.6 KiB
  __shared__ float  lred[4];

  float* wlds = (float*)wlds4;
  const int t  = threadIdx.x;
  const int l  = t & 63;
  const int wv = t >> 6;

  // stage w into padded LDS (conflict-free quad reads in phase 1)
  for (int i = t; i < NCLASS * DIM; i += NTHREADS) {
    int d = i & 127;
    wlds[(i >> 7) * 144 + d + ((d >> 5) << 2)] = w[i];
  }

  const float4* X4 = (const float4*)X;

  // phase-1 identity: quad of lanes per row; lane covers 32 of D
  const int p1row = (wv << 4) + (l >> 2);
  const int dq    = l & 3;
  // phase-2 identity: 4-column group per thread, 8 rows each
  const int d4p2 = t & 31;
  const int rg   = t >> 5;

  float4 g[10];
  #pragma unroll
  for (int c = 0; c < 10; ++c) g[c] = make_float4(0.f, 0.f, 0.f, 0.f);
  float loss_acc = 0.f;

  for (int tix = blockIdx.x; tix < ntiles; tix += gridDim.x) {
    const int row0 = tix * TILE;
    __syncthreads();                       // xs free to overwrite
    // ---- stage X tile (32 x 1KiB async copies, 8 per wave) ----
    #pragma unroll
    for (int ii = 0; ii < 8; ++ii) {
      int i   = (wv << 3) + ii;
      int row = (i << 1) + (l >> 5);
      int d4  = (l & 31) ^ (row & 31);
      async_ld16(X4 + (size_t)(row0 + row) * 32 + d4, xs + (i << 6) + l);
    }
    __syncthreads();                       // staging drained (vmcnt0 before barrier)

    // ---- phase 1: scores ----
    float s[10];
    #pragma unroll
    for (int c = 0; c < 10; ++c) s[c] = 0.f;
    #pragma unroll
    for (int j = 0; j < 8; ++j) {
      int d4 = (dq << 3) + j;
      float4 x4 = xs[(p1row << 5) + (d4 ^ (p1row & 31))];
      #pragma unroll
      for (int c = 0; c < 10; ++c) {
        float4 w4 = wlds4[c * 36 + dq * 9 + j];
        s[c] = fmaf(x4.x, w4.x, fmaf(x4.y, w4.y,
               fmaf(x4.z, w4.z, fmaf(x4.w, w4.w, s[c]))));
      }
    }
    #pragma unroll
    for (int c = 0; c < 10; ++c) {        // quad butterfly: full dot in all 4 lanes
      s[c] += __shfl_xor(s[c], 1);
      s[c] += __shfl_xor(s[c], 2);
    }

    int yv = y[row0 + p1row];
    float sy = s[0];
    #pragma unroll
    for (int c = 1; c < 10; ++c) sy = (c == yv) ? s[c] : sy;

    float cnt = 0.f, rl = 0.f;
    float cf[10];
    #pragma unroll
    for (int c = 0; c < 10; ++c) {
      float m = s[c] - sy + 1.0f;
      bool act = (m > 0.f) && (c != yv);
      cf[c] = act ? -1.f : 0.f;
      cnt += act ? 1.f : 0.f;
      rl  += act ? m : 0.f;
    }
    #pragma unroll
    for (int c = 0; c < 10; ++c) cf[c] = (c == yv) ? cnt : cf[c];
    // 4 quad lanes write identical data to the same address (benign)
    coefs[p1row * 3 + 0] = make_float4(cf[0], cf[1], cf[2], cf[3]);
    coefs[p1row * 3 + 1] = make_float4(cf[4], cf[5], cf[6], cf[7]);
    coefs[p1row * 3 + 2] = make_float4(cf[8], cf[9], 0.f, 0.f);
    if (dq == 0) loss_acc += rl;
    __syncthreads();                       // coefs ready

    // ---- phase 2: grad outer-product accumulate ----
    #pragma unroll
    for (int k = 0; k < 8; ++k) {
      int r = (k << 3) + rg;
      float4 x4 = xs[(r << 5) + (d4p2 ^ (r & 31))];
      float4 c0 = coefs[r * 3 + 0];
      float4 c1 = coefs[r * 3 + 1];
      float4 c2 = coefs[r * 3 + 2];
#define ACC4(cc, gi)                         \
      g[gi].x = fmaf(cc, x4.x, g[gi].x);     \
      g[gi].y = fmaf(cc, x4.y, g[gi].y);     \
      g[gi].z = fmaf(cc, x4.z, g[gi].z);     \
      g[gi].w = fmaf(cc, x4.w, g[gi].w);
      ACC4(c0.x, 0) ACC4(c0.y, 1) ACC4(c0.z, 2) ACC4(c0.w, 3)
      ACC4(c1.x, 4) ACC4(c1.y, 5) ACC4(c1.z, 6) ACC4(c1.w, 7)
      ACC4(c2.x, 8) ACC4(c2.y, 9)
#undef ACC4
    }
  }

  // ---- loss reduction ----
  float contrib = loss_acc * inv_n;
  if (blockIdx.x == 0) {                   // block 0 adds the reg terms
    float rw = 0.f;
    for (int i = t; i < NCLASS * DIM; i += NTHREADS) rw = fmaf(w[i], w[i], rw);
    contrib = fmaf(0.5f * REG_CONST, rw, contrib);
  }
  #pragma unroll
  for (int off = 32; off; off >>= 1) contrib += __shfl_down(contrib, off);
  if (l == 0) lred[wv] = contrib;
  __syncthreads();                         // also guards xs reuse below
  if (t == 0) atomicAdd(out + NCLASS * DIM, lred[0] + lred[1] + lred[2] + lred[3]);

  // ---- grad reduction: 8-way over row-groups, then atomics ----
  float4* red = xs;
  #pragma unroll
  for (int chunk = 0; chunk < 2; ++chunk) {
    __syncthreads();
    #pragma unroll
    for (int k = 0; k < 5; ++k) red[k * 256 + t] = g[chunk * 5 + k];
    __syncthreads();
    if (t < 160) {
      int k = t >> 5, dd = t & 31;
      float sx = 0.f, syy = 0.f, sz = 0.f, sw = 0.f;
      #pragma unroll
      for (int r8 = 0; r8 < 8; ++r8) {
        float4 v = red[k * 256 + (r8 << 5) + dd];
        sx += v.x; syy += v.y; sz += v.z; sw += v.w;
      }
      int c = chunk * 5 + k;
      int base = c * DIM + (dd << 2);
      float ax = sx * inv_n, ay = syy * inv_n, az = sz * inv_n, aw = sw * inv_n;
      if (blockIdx.x == 0) {
        ax += REG_CONST * w[base + 0];
        ay += REG_CONST * w[base + 1];
        az += REG_CONST * w[base + 2];
        aw += REG_CONST * w[base + 3];
      }
      atomicAdd(out + base + 0, ax);
      atomicAdd(out + base + 1, ay);
      atomicAdd(out + base + 2, az);
      atomicAdd(out + base + 3, aw);
    }
  }
}

extern "C" void kernel_launch(void* const* d_in, const int* in_sizes, int n_in,
                              void* d_out, int out_size, void* d_ws, size_t ws_size,
                              hipStream_t stream) {
  const float* X = (const float*)d_in[0];
  const int*   y = (const int*)d_in[1];
  const float* w = (const float*)d_in[2];
  float* out = (float*)d_out;
  int N = in_sizes[1];                 // y element count = 1,000,000
  int ntiles = N / TILE;               // 15625 (N divisible by 64)
  float inv_n = 1.0f / (float)N;
  hipMemsetAsync(d_out, 0, (size_t)out_size * sizeof(float), stream);
  svm_fused<<<NBLOCKS, NTHREADS, 0, stream>>>(X, y, w, out, ntiles, inv_n);
}